// Round 1
// baseline (2339.367 us; speedup 1.0000x reference)
//
#include <hip/hip_runtime.h>
#include <hip/hip_bf16.h>
#include <math.h>

#define TT 8192
#define HD 1024
#define FHD 4096
#define NE 8

typedef short s16x8 __attribute__((ext_vector_type(8)));
typedef float f32x4 __attribute__((ext_vector_type(4)));
using bf16 = __hip_bfloat16;

// workspace layout (bytes)
#define OFF_COUNTS 0
#define OFF_CURSOR 64
#define OFF_OFFS   128
#define OFF_E0     256
#define OFF_E1     (OFF_E0 + 4*TT)
#define OFF_W0     (OFF_E1 + 4*TT)
#define OFF_W1     (OFF_W0 + 4*TT)
#define OFF_TID    (OFF_W1 + 4*TT)
#define OFF_TW     (OFF_TID + 8*TT)
#define OFF_XBF    (OFF_TW + 8*TT)
#define OFF_HMID   (OFF_XBF + 2*TT*HD)

#define BM 128
#define BN 128
#define BK 32
#define LDT 40   // padded LDS leading dim (bf16 elems): stride 80B -> ~2-way on frag reads

__global__ __launch_bounds__(256) void cast_x_kernel(const float* __restrict__ x, bf16* __restrict__ xbf) {
    int i = (blockIdx.x * 256 + threadIdx.x) * 8;
    float4 a = *reinterpret_cast<const float4*>(&x[i]);
    float4 b = *reinterpret_cast<const float4*>(&x[i + 4]);
    bf16 h[8];
    h[0] = __float2bfloat16(a.x); h[1] = __float2bfloat16(a.y);
    h[2] = __float2bfloat16(a.z); h[3] = __float2bfloat16(a.w);
    h[4] = __float2bfloat16(b.x); h[5] = __float2bfloat16(b.y);
    h[6] = __float2bfloat16(b.z); h[7] = __float2bfloat16(b.w);
    *reinterpret_cast<uint4*>(&xbf[i]) = *reinterpret_cast<uint4*>(h);
}

__global__ __launch_bounds__(256) void router_kernel(const float* __restrict__ x,
        const float* __restrict__ rw, const float* __restrict__ rb,
        int* __restrict__ e0a, int* __restrict__ e1a,
        float* __restrict__ w0a, float* __restrict__ w1a, int* __restrict__ counts) {
    int wid = threadIdx.x >> 6, lane = threadIdx.x & 63;
    int t = blockIdx.x * 4 + wid;
    const float* xp = x + (size_t)t * HD + lane * 16;
    float xv[16];
#pragma unroll
    for (int j = 0; j < 4; ++j) {
        float4 v = *reinterpret_cast<const float4*>(&xp[j * 4]);
        xv[4 * j] = v.x; xv[4 * j + 1] = v.y; xv[4 * j + 2] = v.z; xv[4 * j + 3] = v.w;
    }
    float acc[8] = {0.f, 0.f, 0.f, 0.f, 0.f, 0.f, 0.f, 0.f};
    const float* rp = rw + (size_t)(lane * 16) * NE;
#pragma unroll
    for (int hh = 0; hh < 16; ++hh) {
        float4 r0 = *reinterpret_cast<const float4*>(&rp[hh * 8]);
        float4 r1 = *reinterpret_cast<const float4*>(&rp[hh * 8 + 4]);
        acc[0] += xv[hh] * r0.x; acc[1] += xv[hh] * r0.y;
        acc[2] += xv[hh] * r0.z; acc[3] += xv[hh] * r0.w;
        acc[4] += xv[hh] * r1.x; acc[5] += xv[hh] * r1.y;
        acc[6] += xv[hh] * r1.z; acc[7] += xv[hh] * r1.w;
    }
#pragma unroll
    for (int e = 0; e < 8; ++e) {
#pragma unroll
        for (int off = 32; off > 0; off >>= 1) acc[e] += __shfl_xor(acc[e], off, 64);
    }
    if (lane == 0) {
        float lg[8];
#pragma unroll
        for (int e = 0; e < 8; ++e) lg[e] = acc[e] + rb[e];
        int a = 0;
#pragma unroll
        for (int e = 1; e < 8; ++e) if (lg[e] > lg[a]) a = e;
        int b = (a == 0) ? 1 : 0;
#pragma unroll
        for (int e = 0; e < 8; ++e) if (e != a && e != b && lg[e] > lg[b]) b = e;
        float wa = 1.0f / (1.0f + expf(lg[b] - lg[a]));
        float wb = 1.0f / (1.0f + expf(lg[a] - lg[b]));
        e0a[t] = a; e1a[t] = b; w0a[t] = wa; w1a[t] = wb;
        atomicAdd(&counts[a], 1);
        atomicAdd(&counts[b], 1);
    }
}

__global__ void scan_offsets_kernel(const int* __restrict__ counts, int* __restrict__ offs, int* __restrict__ cursor) {
    if (threadIdx.x == 0 && blockIdx.x == 0) {
        int s = 0;
        for (int e = 0; e < NE; ++e) { offs[e] = s; cursor[e] = s; s += counts[e]; }
        offs[NE] = s;
    }
}

__global__ __launch_bounds__(256) void scatter_kernel(const int* __restrict__ e0a, const int* __restrict__ e1a,
        const float* __restrict__ w0a, const float* __restrict__ w1a,
        int* __restrict__ cursor, int* __restrict__ tid_arr, float* __restrict__ tw_arr) {
    int t = blockIdx.x * 256 + threadIdx.x;
    int s0 = atomicAdd(&cursor[e0a[t]], 1);
    tid_arr[s0] = t; tw_arr[s0] = w0a[t];
    int s1 = atomicAdd(&cursor[e1a[t]], 1);
    tid_arr[s1] = t; tw_arr[s1] = w1a[t];
}

// GEMM1: hmid[slot, :] = gelu( x[tok[slot], :] @ w1[e] + b1[e] ), bf16 out
__global__ __launch_bounds__(256) void gemm1_kernel(const bf16* __restrict__ xbf, const float* __restrict__ w1,
        const float* __restrict__ b1, const int* __restrict__ offs,
        const int* __restrict__ tid_arr, bf16* __restrict__ hmid) {
    __shared__ bf16 As[BM][LDT];
    __shared__ bf16 Bs[BN][LDT];
    __shared__ int toks[BM];
    const int NT = FHD / BN;  // 32
    const int MT = TT / BM;   // 64
    int e = blockIdx.x / (NT * MT);
    int rem = blockIdx.x % (NT * MT);
    int nt = rem / MT;
    int mt = rem % MT;
    int s0 = offs[e], s1 = offs[e + 1];
    int row0 = s0 + mt * BM;
    if (row0 >= s1) return;
    int n0 = nt * BN;
    int tid = threadIdx.x;
    if (tid < BM) { int s = row0 + tid; toks[tid] = tid_arr[(s < s1) ? s : (s1 - 1)]; }
    __syncthreads();
    int lane = tid & 63, wid = tid >> 6;
    int wrow = (wid >> 1) * 64, wcol = (wid & 1) * 64;
    int lr = lane & 15, lk = (lane >> 4) * 8;
    f32x4 acc[4][4] = {};
    const float* w1e = w1 + (size_t)e * HD * FHD;
    for (int k0 = 0; k0 < HD; k0 += BK) {
#pragma unroll
        for (int i = 0; i < 2; ++i) {
            int lin = tid + i * 256;
            int r = lin >> 2, seg = lin & 3;
            *reinterpret_cast<uint4*>(&As[r][seg * 8]) =
                *reinterpret_cast<const uint4*>(&xbf[(size_t)toks[r] * HD + k0 + seg * 8]);
        }
#pragma unroll
        for (int i = 0; i < 4; ++i) {
            int lin = tid + i * 256;
            int k = lin >> 5, ng = lin & 31;
            float4 v = *reinterpret_cast<const float4*>(&w1e[(size_t)(k0 + k) * FHD + n0 + ng * 4]);
            float vv[4] = {v.x, v.y, v.z, v.w};
#pragma unroll
            for (int j = 0; j < 4; ++j) {
                int jj = (j + lane) & 3;  // rotate to spread LDS banks
                Bs[ng * 4 + jj][k] = __float2bfloat16(vv[jj]);
            }
        }
        __syncthreads();
        s16x8 aF[4], bF[4];
#pragma unroll
        for (int m = 0; m < 4; ++m) aF[m] = *reinterpret_cast<const s16x8*>(&As[wrow + m * 16 + lr][lk]);
#pragma unroll
        for (int n = 0; n < 4; ++n) bF[n] = *reinterpret_cast<const s16x8*>(&Bs[wcol + n * 16 + lr][lk]);
#pragma unroll
        for (int m = 0; m < 4; ++m)
#pragma unroll
            for (int n = 0; n < 4; ++n)
                acc[m][n] = __builtin_amdgcn_mfma_f32_16x16x32_bf16(aF[m], bF[n], acc[m][n], 0, 0, 0);
        __syncthreads();
    }
#pragma unroll
    for (int m = 0; m < 4; ++m) {
#pragma unroll
        for (int n = 0; n < 4; ++n) {
            int col = n0 + wcol + n * 16 + lr;
            float bv = b1[(size_t)e * FHD + col];
#pragma unroll
            for (int r = 0; r < 4; ++r) {
                int row = wrow + m * 16 + (lane >> 4) * 4 + r;
                int slot = row0 + row;
                if (slot < s1) {
                    float v2 = acc[m][n][r] + bv;
                    v2 = 0.5f * v2 * (1.0f + erff(v2 * 0.70710678118f));
                    hmid[(size_t)slot * FHD + col] = __float2bfloat16(v2);
                }
            }
        }
    }
}

// GEMM2: out[tok[slot], :] += w[slot] * ( hmid[slot, :] @ w2[e] + b2[e] )
__global__ __launch_bounds__(256) void gemm2_kernel(const bf16* __restrict__ hmid, const float* __restrict__ w2,
        const float* __restrict__ b2, const int* __restrict__ offs,
        const int* __restrict__ tid_arr, const float* __restrict__ tw_arr, float* __restrict__ out) {
    __shared__ bf16 As[BM][LDT];
    __shared__ bf16 Bs[BN][LDT];
    __shared__ int toks[BM];
    __shared__ float tws[BM];
    const int NT = HD / BN;  // 8
    const int MT = TT / BM;  // 64
    int e = blockIdx.x / (NT * MT);
    int rem = blockIdx.x % (NT * MT);
    int nt = rem / MT;
    int mt = rem % MT;
    int s0 = offs[e], s1 = offs[e + 1];
    int row0 = s0 + mt * BM;
    if (row0 >= s1) return;
    int n0 = nt * BN;
    int tid = threadIdx.x;
    if (tid < BM) {
        int s = row0 + tid;
        int sc = (s < s1) ? s : (s1 - 1);
        toks[tid] = tid_arr[sc];
        tws[tid] = tw_arr[sc];
    }
    __syncthreads();
    int lane = tid & 63, wid = tid >> 6;
    int wrow = (wid >> 1) * 64, wcol = (wid & 1) * 64;
    int lr = lane & 15, lk = (lane >> 4) * 8;
    f32x4 acc[4][4] = {};
    const float* w2e = w2 + (size_t)e * FHD * HD;
    for (int k0 = 0; k0 < FHD; k0 += BK) {
#pragma unroll
        for (int i = 0; i < 2; ++i) {
            int lin = tid + i * 256;
            int r = lin >> 2, seg = lin & 3;
            int sr = row0 + r; if (sr >= s1) sr = s1 - 1;
            *reinterpret_cast<uint4*>(&As[r][seg * 8]) =
                *reinterpret_cast<const uint4*>(&hmid[(size_t)sr * FHD + k0 + seg * 8]);
        }
#pragma unroll
        for (int i = 0; i < 4; ++i) {
            int lin = tid + i * 256;
            int k = lin >> 5, ng = lin & 31;
            float4 v = *reinterpret_cast<const float4*>(&w2e[(size_t)(k0 + k) * HD + n0 + ng * 4]);
            float vv[4] = {v.x, v.y, v.z, v.w};
#pragma unroll
            for (int j = 0; j < 4; ++j) {
                int jj = (j + lane) & 3;
                Bs[ng * 4 + jj][k] = __float2bfloat16(vv[jj]);
            }
        }
        __syncthreads();
        s16x8 aF[4], bF[4];
#pragma unroll
        for (int m = 0; m < 4; ++m) aF[m] = *reinterpret_cast<const s16x8*>(&As[wrow + m * 16 + lr][lk]);
#pragma unroll
        for (int n = 0; n < 4; ++n) bF[n] = *reinterpret_cast<const s16x8*>(&Bs[wcol + n * 16 + lr][lk]);
#pragma unroll
        for (int m = 0; m < 4; ++m)
#pragma unroll
            for (int n = 0; n < 4; ++n)
                acc[m][n] = __builtin_amdgcn_mfma_f32_16x16x32_bf16(aF[m], bF[n], acc[m][n], 0, 0, 0);
        __syncthreads();
    }
#pragma unroll
    for (int m = 0; m < 4; ++m) {
#pragma unroll
        for (int n = 0; n < 4; ++n) {
            int col = n0 + wcol + n * 16 + lr;
            float bv = b2[(size_t)e * HD + col];
#pragma unroll
            for (int r = 0; r < 4; ++r) {
                int row = wrow + m * 16 + (lane >> 4) * 4 + r;
                int slot = row0 + row;
                if (slot < s1) {
                    float y = acc[m][n][r] + bv;
                    atomicAdd(&out[(size_t)toks[row] * HD + col], tws[row] * y);
                }
            }
        }
    }
}

extern "C" void kernel_launch(void* const* d_in, const int* in_sizes, int n_in,
                              void* d_out, int out_size, void* d_ws, size_t ws_size,
                              hipStream_t stream) {
    const float* x  = (const float*)d_in[0];
    const float* rw = (const float*)d_in[1];
    const float* rb = (const float*)d_in[2];
    const float* w1 = (const float*)d_in[3];
    const float* b1 = (const float*)d_in[4];
    const float* w2 = (const float*)d_in[5];
    const float* b2 = (const float*)d_in[6];
    float* out = (float*)d_out;
    char* ws = (char*)d_ws;

    int*   counts  = (int*)(ws + OFF_COUNTS);
    int*   cursor  = (int*)(ws + OFF_CURSOR);
    int*   offs    = (int*)(ws + OFF_OFFS);
    int*   e0a     = (int*)(ws + OFF_E0);
    int*   e1a     = (int*)(ws + OFF_E1);
    float* w0a     = (float*)(ws + OFF_W0);
    float* w1a     = (float*)(ws + OFF_W1);
    int*   tid_arr = (int*)(ws + OFF_TID);
    float* tw_arr  = (float*)(ws + OFF_TW);
    bf16*  xbf     = (bf16*)(ws + OFF_XBF);
    bf16*  hmid    = (bf16*)(ws + OFF_HMID);

    hipMemsetAsync(counts, 0, 64, stream);                       // counts
    hipMemsetAsync(out, 0, (size_t)TT * HD * sizeof(float), stream);

    cast_x_kernel<<<TT * HD / 2048, 256, 0, stream>>>(x, xbf);
    router_kernel<<<TT / 4, 256, 0, stream>>>(x, rw, rb, e0a, e1a, w0a, w1a, counts);
    scan_offsets_kernel<<<1, 64, 0, stream>>>(counts, offs, cursor);
    scatter_kernel<<<TT / 256, 256, 0, stream>>>(e0a, e1a, w0a, w1a, cursor, tid_arr, tw_arr);
    gemm1_kernel<<<NE * (FHD / BN) * (TT / BM), 256, 0, stream>>>(xbf, w1, b1, offs, tid_arr, hmid);
    gemm2_kernel<<<NE * (HD / BN) * (TT / BM), 256, 0, stream>>>(hmid, w2, b2, offs, tid_arr, tw_arr, out);
}

// Round 2
// 1183.982 us; speedup vs baseline: 1.9758x; 1.9758x over previous
//
#include <hip/hip_runtime.h>
#include <hip/hip_bf16.h>
#include <math.h>

#define TT 8192
#define HD 1024
#define FHD 4096
#define NE 8

typedef short s16x8 __attribute__((ext_vector_type(8)));
typedef float f32x4 __attribute__((ext_vector_type(4)));
using bf16 = __hip_bfloat16;
typedef unsigned int u32;

// workspace layout (bytes)
#define OFF_COUNTS 0
#define OFF_CURSOR 64
#define OFF_OFFS   128
#define OFF_E0     256
#define OFF_E1     (OFF_E0 + 4*TT)
#define OFF_W0     (OFF_E1 + 4*TT)
#define OFF_W1     (OFF_W0 + 4*TT)
#define OFF_S0     (OFF_W1 + 4*TT)
#define OFF_S1     (OFF_S0 + 4*TT)
#define OFF_TID    (OFF_S1 + 4*TT)
#define OFF_TW     (OFF_TID + 8*TT)
#define OFF_XBF    (OFF_TW + 8*TT)
#define OFF_W1T    (OFF_XBF + 2*TT*HD)
#define OFF_W2T    (OFF_W1T + 2*NE*HD*FHD)
#define OFF_HMID   (OFF_W2T + 2*NE*HD*FHD)
#define OFF_YS     (OFF_HMID + (size_t)2*(2*TT)*FHD)

#define BM 128
#define BN 128
#define BK 32

__device__ __forceinline__ void gload_lds16(const void* g, void* l) {
    __builtin_amdgcn_global_load_lds(
        (const __attribute__((address_space(1))) u32*)g,
        (__attribute__((address_space(3))) u32*)l, 16, 0, 0);
}

__global__ __launch_bounds__(256) void cast_x_kernel(const float* __restrict__ x, bf16* __restrict__ xbf) {
    int i = (blockIdx.x * 256 + threadIdx.x) * 8;
    float4 a = *reinterpret_cast<const float4*>(&x[i]);
    float4 b = *reinterpret_cast<const float4*>(&x[i + 4]);
    bf16 h[8];
    h[0] = __float2bfloat16(a.x); h[1] = __float2bfloat16(a.y);
    h[2] = __float2bfloat16(a.z); h[3] = __float2bfloat16(a.w);
    h[4] = __float2bfloat16(b.x); h[5] = __float2bfloat16(b.y);
    h[6] = __float2bfloat16(b.z); h[7] = __float2bfloat16(b.w);
    *reinterpret_cast<uint4*>(&xbf[i]) = *reinterpret_cast<uint4*>(h);
}

// transpose+cast: out[c][r] = bf16(in[r][c]); per-expert matrices of shape [R][C].
__global__ __launch_bounds__(256) void transpose_cast_kernel(const float* __restrict__ in,
        bf16* __restrict__ out, int R, int C) {
    __shared__ float tile[64][65];
    int rt = R >> 6, ct = C >> 6;
    int e = blockIdx.x / (rt * ct);
    int rem = blockIdx.x % (rt * ct);
    int r0 = (rem / ct) << 6, c0 = (rem % ct) << 6;
    const float* ine = in + (size_t)e * R * C;
    bf16* oute = out + (size_t)e * R * C;
    int tid = threadIdx.x;
#pragma unroll
    for (int i = 0; i < 4; ++i) {
        int lin = tid + i * 256;
        int r = lin >> 4, cg = lin & 15;
        float4 v = *reinterpret_cast<const float4*>(&ine[(size_t)(r0 + r) * C + c0 + cg * 4]);
        tile[r][cg * 4 + 0] = v.x; tile[r][cg * 4 + 1] = v.y;
        tile[r][cg * 4 + 2] = v.z; tile[r][cg * 4 + 3] = v.w;
    }
    __syncthreads();
#pragma unroll
    for (int i = 0; i < 4; ++i) {
        int lin = tid + i * 256;
        int n = lin >> 4, kg = lin & 15;
        bf16 h[4];
        h[0] = __float2bfloat16(tile[kg * 4 + 0][n]);
        h[1] = __float2bfloat16(tile[kg * 4 + 1][n]);
        h[2] = __float2bfloat16(tile[kg * 4 + 2][n]);
        h[3] = __float2bfloat16(tile[kg * 4 + 3][n]);
        *reinterpret_cast<uint2*>(&oute[(size_t)(c0 + n) * R + r0 + kg * 4]) =
            *reinterpret_cast<uint2*>(h);
    }
}

__global__ __launch_bounds__(256) void router_kernel(const float* __restrict__ x,
        const float* __restrict__ rw, const float* __restrict__ rb,
        int* __restrict__ e0a, int* __restrict__ e1a,
        float* __restrict__ w0a, float* __restrict__ w1a, int* __restrict__ counts) {
    int wid = threadIdx.x >> 6, lane = threadIdx.x & 63;
    int t = blockIdx.x * 4 + wid;
    const float* xp = x + (size_t)t * HD + lane * 16;
    float xv[16];
#pragma unroll
    for (int j = 0; j < 4; ++j) {
        float4 v = *reinterpret_cast<const float4*>(&xp[j * 4]);
        xv[4 * j] = v.x; xv[4 * j + 1] = v.y; xv[4 * j + 2] = v.z; xv[4 * j + 3] = v.w;
    }
    float acc[8] = {0.f, 0.f, 0.f, 0.f, 0.f, 0.f, 0.f, 0.f};
    const float* rp = rw + (size_t)(lane * 16) * NE;
#pragma unroll
    for (int hh = 0; hh < 16; ++hh) {
        float4 r0 = *reinterpret_cast<const float4*>(&rp[hh * 8]);
        float4 r1 = *reinterpret_cast<const float4*>(&rp[hh * 8 + 4]);
        acc[0] += xv[hh] * r0.x; acc[1] += xv[hh] * r0.y;
        acc[2] += xv[hh] * r0.z; acc[3] += xv[hh] * r0.w;
        acc[4] += xv[hh] * r1.x; acc[5] += xv[hh] * r1.y;
        acc[6] += xv[hh] * r1.z; acc[7] += xv[hh] * r1.w;
    }
#pragma unroll
    for (int e = 0; e < 8; ++e) {
#pragma unroll
        for (int off = 32; off > 0; off >>= 1) acc[e] += __shfl_xor(acc[e], off, 64);
    }
    if (lane == 0) {
        float lg[8];
#pragma unroll
        for (int e = 0; e < 8; ++e) lg[e] = acc[e] + rb[e];
        int a = 0;
#pragma unroll
        for (int e = 1; e < 8; ++e) if (lg[e] > lg[a]) a = e;
        int b = (a == 0) ? 1 : 0;
#pragma unroll
        for (int e = 0; e < 8; ++e) if (e != a && e != b && lg[e] > lg[b]) b = e;
        float wa = 1.0f / (1.0f + expf(lg[b] - lg[a]));
        float wb = 1.0f / (1.0f + expf(lg[a] - lg[b]));
        e0a[t] = a; e1a[t] = b; w0a[t] = wa; w1a[t] = wb;
        atomicAdd(&counts[a], 1);
        atomicAdd(&counts[b], 1);
    }
}

__global__ void scan_offsets_kernel(const int* __restrict__ counts, int* __restrict__ offs, int* __restrict__ cursor) {
    if (threadIdx.x == 0 && blockIdx.x == 0) {
        int s = 0;
        for (int e = 0; e < NE; ++e) { offs[e] = s; cursor[e] = s; s += counts[e]; }
        offs[NE] = s;
    }
}

__global__ __launch_bounds__(256) void scatter_kernel(const int* __restrict__ e0a, const int* __restrict__ e1a,
        const float* __restrict__ w0a, const float* __restrict__ w1a,
        int* __restrict__ cursor, int* __restrict__ tid_arr, float* __restrict__ tw_arr,
        int* __restrict__ slot0, int* __restrict__ slot1) {
    int t = blockIdx.x * 256 + threadIdx.x;
    int s0 = atomicAdd(&cursor[e0a[t]], 1);
    tid_arr[s0] = t; tw_arr[s0] = w0a[t]; slot0[t] = s0;
    int s1 = atomicAdd(&cursor[e1a[t]], 1);
    tid_arr[s1] = t; tw_arr[s1] = w1a[t]; slot1[t] = s1;
}

// GEMM1: hmid[slot, :] = gelu( x[tok[slot], :] @ w1t[e]^T + b1[e] ), bf16 out
// A = gathered xbf rows, B = w1t[e] rows ([N][K] layout), both staged via global_load_lds.
__global__ __launch_bounds__(256) void gemm1_kernel(const bf16* __restrict__ xbf, const bf16* __restrict__ w1t,
        const float* __restrict__ b1, const int* __restrict__ offs,
        const int* __restrict__ tid_arr, bf16* __restrict__ hmid) {
    __shared__ bf16 As[BM * BK];
    __shared__ bf16 Bs[BN * BK];
    __shared__ int toks[BM];
    const int NT = FHD / BN;  // 32
    const int MT = TT / BM;   // 64
    int e = blockIdx.x / (NT * MT);
    int rem = blockIdx.x % (NT * MT);
    int nt = rem / MT;
    int mt = rem % MT;
    int s0 = offs[e], s1 = offs[e + 1];
    int row0 = s0 + mt * BM;
    if (row0 >= s1) return;
    int n0 = nt * BN;
    int tid = threadIdx.x;
    if (tid < BM) { int s = row0 + tid; toks[tid] = tid_arr[(s < s1) ? s : (s1 - 1)]; }
    __syncthreads();
    int lane = tid & 63, w = tid >> 6;
    int wrow = (w >> 1) * 64, wcol = (w & 1) * 64;
    int lr = lane & 15, lk = (lane >> 4) * 8;
    int srow = lane >> 2, seg = lane & 3;        // staging: 16 rows/issue, 4 lanes/row
    int tokA0 = toks[w * 32 + srow];
    int tokA1 = toks[w * 32 + 16 + srow];
    const bf16* w1e = w1t + (size_t)e * FHD * HD;
    const bf16* bsrc0 = w1e + (size_t)(n0 + w * 32 + srow) * HD + seg * 8;
    const bf16* bsrc1 = w1e + (size_t)(n0 + w * 32 + 16 + srow) * HD + seg * 8;
    const bf16* asrc0 = xbf + (size_t)tokA0 * HD + seg * 8;
    const bf16* asrc1 = xbf + (size_t)tokA1 * HD + seg * 8;
    bf16* aDst0 = &As[(w * 32) * BK];
    bf16* aDst1 = &As[(w * 32 + 16) * BK];
    bf16* bDst0 = &Bs[(w * 32) * BK];
    bf16* bDst1 = &Bs[(w * 32 + 16) * BK];
    f32x4 acc[4][4] = {};
    for (int k0 = 0; k0 < HD; k0 += BK) {
        gload_lds16(asrc0 + k0, aDst0);
        gload_lds16(asrc1 + k0, aDst1);
        gload_lds16(bsrc0 + k0, bDst0);
        gload_lds16(bsrc1 + k0, bDst1);
        __syncthreads();
        s16x8 aF[4], bF[4];
#pragma unroll
        for (int m = 0; m < 4; ++m) aF[m] = *reinterpret_cast<const s16x8*>(&As[(wrow + m * 16 + lr) * BK + lk]);
#pragma unroll
        for (int n = 0; n < 4; ++n) bF[n] = *reinterpret_cast<const s16x8*>(&Bs[(wcol + n * 16 + lr) * BK + lk]);
#pragma unroll
        for (int m = 0; m < 4; ++m)
#pragma unroll
            for (int n = 0; n < 4; ++n)
                acc[m][n] = __builtin_amdgcn_mfma_f32_16x16x32_bf16(aF[m], bF[n], acc[m][n], 0, 0, 0);
        __syncthreads();
    }
#pragma unroll
    for (int m = 0; m < 4; ++m) {
#pragma unroll
        for (int n = 0; n < 4; ++n) {
            int col = n0 + wcol + n * 16 + lr;
            float bv = b1[(size_t)e * FHD + col];
#pragma unroll
            for (int r = 0; r < 4; ++r) {
                int row = wrow + m * 16 + (lane >> 4) * 4 + r;
                int slot = row0 + row;
                if (slot < s1) {
                    float v2 = acc[m][n][r] + bv;
                    v2 = 0.5f * v2 * (1.0f + erff(v2 * 0.70710678118f));
                    hmid[(size_t)slot * FHD + col] = __float2bfloat16(v2);
                }
            }
        }
    }
}

// GEMM2: ys[slot, :] = hmid[slot, :] @ w2t[e]^T + b2[e]  (f32 out, no scatter)
__global__ __launch_bounds__(256) void gemm2_kernel(const bf16* __restrict__ hmid, const bf16* __restrict__ w2t,
        const float* __restrict__ b2, const int* __restrict__ offs, float* __restrict__ ys) {
    __shared__ bf16 As[BM * BK];
    __shared__ bf16 Bs[BN * BK];
    const int NT = HD / BN;   // 8
    const int MT = TT / BM;   // 64
    int e = blockIdx.x / (NT * MT);
    int rem = blockIdx.x % (NT * MT);
    int nt = rem / MT;
    int mt = rem % MT;
    int s0 = offs[e], s1 = offs[e + 1];
    int row0 = s0 + mt * BM;
    if (row0 >= s1) return;
    int n0 = nt * BN;
    int tid = threadIdx.x;
    int lane = tid & 63, w = tid >> 6;
    int wrow = (w >> 1) * 64, wcol = (w & 1) * 64;
    int lr = lane & 15, lk = (lane >> 4) * 8;
    int srow = lane >> 2, seg = lane & 3;
    int ar0 = row0 + w * 32 + srow;      if (ar0 >= s1) ar0 = s1 - 1;
    int ar1 = row0 + w * 32 + 16 + srow; if (ar1 >= s1) ar1 = s1 - 1;
    const bf16* w2e = w2t + (size_t)e * HD * FHD;
    const bf16* bsrc0 = w2e + (size_t)(n0 + w * 32 + srow) * FHD + seg * 8;
    const bf16* bsrc1 = w2e + (size_t)(n0 + w * 32 + 16 + srow) * FHD + seg * 8;
    const bf16* asrc0 = hmid + (size_t)ar0 * FHD + seg * 8;
    const bf16* asrc1 = hmid + (size_t)ar1 * FHD + seg * 8;
    bf16* aDst0 = &As[(w * 32) * BK];
    bf16* aDst1 = &As[(w * 32 + 16) * BK];
    bf16* bDst0 = &Bs[(w * 32) * BK];
    bf16* bDst1 = &Bs[(w * 32 + 16) * BK];
    f32x4 acc[4][4] = {};
    for (int k0 = 0; k0 < FHD; k0 += BK) {
        gload_lds16(asrc0 + k0, aDst0);
        gload_lds16(asrc1 + k0, aDst1);
        gload_lds16(bsrc0 + k0, bDst0);
        gload_lds16(bsrc1 + k0, bDst1);
        __syncthreads();
        s16x8 aF[4], bF[4];
#pragma unroll
        for (int m = 0; m < 4; ++m) aF[m] = *reinterpret_cast<const s16x8*>(&As[(wrow + m * 16 + lr) * BK + lk]);
#pragma unroll
        for (int n = 0; n < 4; ++n) bF[n] = *reinterpret_cast<const s16x8*>(&Bs[(wcol + n * 16 + lr) * BK + lk]);
#pragma unroll
        for (int m = 0; m < 4; ++m)
#pragma unroll
            for (int n = 0; n < 4; ++n)
                acc[m][n] = __builtin_amdgcn_mfma_f32_16x16x32_bf16(aF[m], bF[n], acc[m][n], 0, 0, 0);
        __syncthreads();
    }
#pragma unroll
    for (int m = 0; m < 4; ++m) {
#pragma unroll
        for (int n = 0; n < 4; ++n) {
            int col = n0 + wcol + n * 16 + lr;
            float bv = b2[(size_t)e * HD + col];
#pragma unroll
            for (int r = 0; r < 4; ++r) {
                int row = wrow + m * 16 + (lane >> 4) * 4 + r;
                int slot = row0 + row;
                if (slot < s1) ys[(size_t)slot * HD + col] = acc[m][n][r] + bv;
            }
        }
    }
}

// out[t,:] = tw[slot0[t]] * ys[slot0[t],:] + tw[slot1[t]] * ys[slot1[t],:]
__global__ __launch_bounds__(256) void combine_kernel(const float* __restrict__ ys,
        const int* __restrict__ slot0, const int* __restrict__ slot1,
        const float* __restrict__ tw, float* __restrict__ out) {
    int t = blockIdx.x;
    int c = threadIdx.x * 4;
    int sa = slot0[t], sb = slot1[t];
    float wa = tw[sa], wb = tw[sb];
    float4 a = *reinterpret_cast<const float4*>(&ys[(size_t)sa * HD + c]);
    float4 b = *reinterpret_cast<const float4*>(&ys[(size_t)sb * HD + c]);
    float4 o;
    o.x = wa * a.x + wb * b.x; o.y = wa * a.y + wb * b.y;
    o.z = wa * a.z + wb * b.z; o.w = wa * a.w + wb * b.w;
    *reinterpret_cast<float4*>(&out[(size_t)t * HD + c]) = o;
}

extern "C" void kernel_launch(void* const* d_in, const int* in_sizes, int n_in,
                              void* d_out, int out_size, void* d_ws, size_t ws_size,
                              hipStream_t stream) {
    const float* x  = (const float*)d_in[0];
    const float* rw = (const float*)d_in[1];
    const float* rb = (const float*)d_in[2];
    const float* w1 = (const float*)d_in[3];
    const float* b1 = (const float*)d_in[4];
    const float* w2 = (const float*)d_in[5];
    const float* b2 = (const float*)d_in[6];
    float* out = (float*)d_out;
    char* ws = (char*)d_ws;

    int*   counts  = (int*)(ws + OFF_COUNTS);
    int*   cursor  = (int*)(ws + OFF_CURSOR);
    int*   offs    = (int*)(ws + OFF_OFFS);
    int*   e0a     = (int*)(ws + OFF_E0);
    int*   e1a     = (int*)(ws + OFF_E1);
    float* w0a     = (float*)(ws + OFF_W0);
    float* w1a     = (float*)(ws + OFF_W1);
    int*   slot0   = (int*)(ws + OFF_S0);
    int*   slot1   = (int*)(ws + OFF_S1);
    int*   tid_arr = (int*)(ws + OFF_TID);
    float* tw_arr  = (float*)(ws + OFF_TW);
    bf16*  xbf     = (bf16*)(ws + OFF_XBF);
    bf16*  w1t     = (bf16*)(ws + OFF_W1T);
    bf16*  w2t     = (bf16*)(ws + OFF_W2T);
    bf16*  hmid    = (bf16*)(ws + OFF_HMID);
    float* ys      = (float*)(ws + OFF_YS);

    hipMemsetAsync(counts, 0, 64, stream);

    cast_x_kernel<<<TT * HD / 2048, 256, 0, stream>>>(x, xbf);
    transpose_cast_kernel<<<NE * (HD / 64) * (FHD / 64), 256, 0, stream>>>(w1, w1t, HD, FHD);
    transpose_cast_kernel<<<NE * (FHD / 64) * (HD / 64), 256, 0, stream>>>(w2, w2t, FHD, HD);
    router_kernel<<<TT / 4, 256, 0, stream>>>(x, rw, rb, e0a, e1a, w0a, w1a, counts);
    scan_offsets_kernel<<<1, 64, 0, stream>>>(counts, offs, cursor);
    scatter_kernel<<<TT / 256, 256, 0, stream>>>(e0a, e1a, w0a, w1a, cursor, tid_arr, tw_arr, slot0, slot1);
    gemm1_kernel<<<NE * (FHD / BN) * (TT / BM), 256, 0, stream>>>(xbf, w1t, b1, offs, tid_arr, hmid);
    gemm2_kernel<<<NE * (HD / BN) * (TT / BM), 256, 0, stream>>>(hmid, w2t, b2, offs, ys);
    combine_kernel<<<TT, 256, 0, stream>>>(ys, slot0, slot1, tw_arr, out);
}

// Round 3
// 929.205 us; speedup vs baseline: 2.5176x; 1.2742x over previous
//
#include <hip/hip_runtime.h>
#include <hip/hip_bf16.h>
#include <math.h>

#define TT 8192
#define HD 1024
#define FHD 4096
#define NE 8
#define NTMAX 136

typedef short s16x8 __attribute__((ext_vector_type(8)));
typedef float f32x4 __attribute__((ext_vector_type(4)));
using bf16 = __hip_bfloat16;
typedef unsigned int u32;

// workspace layout (bytes)
#define OFF_COUNTS 0
#define OFF_CURSOR 64
#define OFF_OFFS   128
#define OFF_E0     256
#define OFF_E1     (OFF_E0 + 4*TT)
#define OFF_W0     (OFF_E1 + 4*TT)
#define OFF_W1     (OFF_W0 + 4*TT)
#define OFF_S0     (OFF_W1 + 4*TT)
#define OFF_S1     (OFF_S0 + 4*TT)
#define OFF_TID    (OFF_S1 + 4*TT)
#define OFF_TW     (OFF_TID + 8*TT)
#define OFF_TMR    (OFF_TW + 8*TT)
#define OFF_TME    (OFF_TMR + 4*144)
#define OFF_TMN    (OFF_TME + 4*144)
#define OFF_XBF    (OFF_TMN + 64)
#define OFF_W1T    (OFF_XBF + 2*TT*HD)
#define OFF_W2T    (OFF_W1T + 2*NE*HD*FHD)
#define OFF_HMID   (OFF_W2T + 2*NE*HD*FHD)
#define OFF_YS     (OFF_HMID + (size_t)2*(2*TT)*FHD)

#define BM 128
#define BN 128
#define BK 32

__device__ __forceinline__ void gload_lds16(const void* g, void* l) {
    __builtin_amdgcn_global_load_lds(
        (const __attribute__((address_space(1))) u32*)g,
        (__attribute__((address_space(3))) u32*)l, 16, 0, 0);
}

__global__ __launch_bounds__(256) void cast_x_kernel(const float* __restrict__ x, bf16* __restrict__ xbf) {
    int i = (blockIdx.x * 256 + threadIdx.x) * 8;
    float4 a = *reinterpret_cast<const float4*>(&x[i]);
    float4 b = *reinterpret_cast<const float4*>(&x[i + 4]);
    bf16 h[8];
    h[0] = __float2bfloat16(a.x); h[1] = __float2bfloat16(a.y);
    h[2] = __float2bfloat16(a.z); h[3] = __float2bfloat16(a.w);
    h[4] = __float2bfloat16(b.x); h[5] = __float2bfloat16(b.y);
    h[6] = __float2bfloat16(b.z); h[7] = __float2bfloat16(b.w);
    *reinterpret_cast<uint4*>(&xbf[i]) = *reinterpret_cast<uint4*>(h);
}

// transpose+cast: out[c][r] = bf16(in[r][c]); per-expert matrices of shape [R][C].
__global__ __launch_bounds__(256) void transpose_cast_kernel(const float* __restrict__ in,
        bf16* __restrict__ out, int R, int C) {
    __shared__ float tile[64][65];
    int rt = R >> 6, ct = C >> 6;
    int e = blockIdx.x / (rt * ct);
    int rem = blockIdx.x % (rt * ct);
    int r0 = (rem / ct) << 6, c0 = (rem % ct) << 6;
    const float* ine = in + (size_t)e * R * C;
    bf16* oute = out + (size_t)e * R * C;
    int tid = threadIdx.x;
#pragma unroll
    for (int i = 0; i < 4; ++i) {
        int lin = tid + i * 256;
        int r = lin >> 4, cg = lin & 15;
        float4 v = *reinterpret_cast<const float4*>(&ine[(size_t)(r0 + r) * C + c0 + cg * 4]);
        tile[r][cg * 4 + 0] = v.x; tile[r][cg * 4 + 1] = v.y;
        tile[r][cg * 4 + 2] = v.z; tile[r][cg * 4 + 3] = v.w;
    }
    __syncthreads();
#pragma unroll
    for (int i = 0; i < 4; ++i) {
        int lin = tid + i * 256;
        int n = lin >> 4, kg = lin & 15;
        bf16 h[4];
        h[0] = __float2bfloat16(tile[kg * 4 + 0][n]);
        h[1] = __float2bfloat16(tile[kg * 4 + 1][n]);
        h[2] = __float2bfloat16(tile[kg * 4 + 2][n]);
        h[3] = __float2bfloat16(tile[kg * 4 + 3][n]);
        *reinterpret_cast<uint2*>(&oute[(size_t)(c0 + n) * R + r0 + kg * 4]) =
            *reinterpret_cast<uint2*>(h);
    }
}

__global__ __launch_bounds__(256) void router_kernel(const float* __restrict__ x,
        const float* __restrict__ rw, const float* __restrict__ rb,
        int* __restrict__ e0a, int* __restrict__ e1a,
        float* __restrict__ w0a, float* __restrict__ w1a, int* __restrict__ counts) {
    int wid = threadIdx.x >> 6, lane = threadIdx.x & 63;
    int t = blockIdx.x * 4 + wid;
    const float* xp = x + (size_t)t * HD + lane * 16;
    float xv[16];
#pragma unroll
    for (int j = 0; j < 4; ++j) {
        float4 v = *reinterpret_cast<const float4*>(&xp[j * 4]);
        xv[4 * j] = v.x; xv[4 * j + 1] = v.y; xv[4 * j + 2] = v.z; xv[4 * j + 3] = v.w;
    }
    float acc[8] = {0.f, 0.f, 0.f, 0.f, 0.f, 0.f, 0.f, 0.f};
    const float* rp = rw + (size_t)(lane * 16) * NE;
#pragma unroll
    for (int hh = 0; hh < 16; ++hh) {
        float4 r0 = *reinterpret_cast<const float4*>(&rp[hh * 8]);
        float4 r1 = *reinterpret_cast<const float4*>(&rp[hh * 8 + 4]);
        acc[0] += xv[hh] * r0.x; acc[1] += xv[hh] * r0.y;
        acc[2] += xv[hh] * r0.z; acc[3] += xv[hh] * r0.w;
        acc[4] += xv[hh] * r1.x; acc[5] += xv[hh] * r1.y;
        acc[6] += xv[hh] * r1.z; acc[7] += xv[hh] * r1.w;
    }
#pragma unroll
    for (int e = 0; e < 8; ++e) {
#pragma unroll
        for (int off = 32; off > 0; off >>= 1) acc[e] += __shfl_xor(acc[e], off, 64);
    }
    if (lane == 0) {
        float lg[8];
#pragma unroll
        for (int e = 0; e < 8; ++e) lg[e] = acc[e] + rb[e];
        int a = 0;
#pragma unroll
        for (int e = 1; e < 8; ++e) if (lg[e] > lg[a]) a = e;
        int b = (a == 0) ? 1 : 0;
#pragma unroll
        for (int e = 0; e < 8; ++e) if (e != a && e != b && lg[e] > lg[b]) b = e;
        float wa = 1.0f / (1.0f + expf(lg[b] - lg[a]));
        float wb = 1.0f / (1.0f + expf(lg[a] - lg[b]));
        e0a[t] = a; e1a[t] = b; w0a[t] = wa; w1a[t] = wb;
        atomicAdd(&counts[a], 1);
        atomicAdd(&counts[b], 1);
    }
}

// builds offsets, cursors, and the compact M-tile map (row0, expert)
__global__ void scan_offsets_kernel(const int* __restrict__ counts, int* __restrict__ offs,
        int* __restrict__ cursor, int* __restrict__ tmr, int* __restrict__ tme,
        int* __restrict__ tmn) {
    if (threadIdx.x == 0 && blockIdx.x == 0) {
        int s = 0, nt = 0;
        for (int e = 0; e < NE; ++e) {
            offs[e] = s; cursor[e] = s;
            int c = counts[e];
            for (int j = 0; j < c; j += BM) { tmr[nt] = s + j; tme[nt] = e; ++nt; }
            s += c;
        }
        offs[NE] = s;
        tmn[0] = nt;
        for (int i = nt; i < NTMAX; ++i) { tmr[i] = 0; tme[i] = 0; }
    }
}

__global__ __launch_bounds__(256) void scatter_kernel(const int* __restrict__ e0a, const int* __restrict__ e1a,
        const float* __restrict__ w0a, const float* __restrict__ w1a,
        int* __restrict__ cursor, int* __restrict__ tid_arr, float* __restrict__ tw_arr,
        int* __restrict__ slot0, int* __restrict__ slot1) {
    int t = blockIdx.x * 256 + threadIdx.x;
    int s0 = atomicAdd(&cursor[e0a[t]], 1);
    tid_arr[s0] = t; tw_arr[s0] = w0a[t]; slot0[t] = s0;
    int s1 = atomicAdd(&cursor[e1a[t]], 1);
    tid_arr[s1] = t; tw_arr[s1] = w1a[t]; slot1[t] = s1;
}

// GEMM1: hmid[slot, :] = gelu( x[tok[slot], :] @ w1t[e]^T + b1[e] ), bf16 out
__global__ __launch_bounds__(256) void gemm1_kernel(const bf16* __restrict__ xbf, const bf16* __restrict__ w1t,
        const float* __restrict__ b1, const int* __restrict__ offs,
        const int* __restrict__ tid_arr, bf16* __restrict__ hmid,
        const int* __restrict__ tmr, const int* __restrict__ tme, const int* __restrict__ tmn) {
    __shared__ bf16 As[BM * BK];
    __shared__ bf16 Bs[BN * BK];
    __shared__ int toks[BM];
    // XCD-bijective swizzle (gridDim.x % 8 == 0): contiguous chunk per XCD
    int nwg = gridDim.x;
    int orig = blockIdx.x;
    int wg = (orig & 7) * (nwg >> 3) + (orig >> 3);
    int nt = wg / NTMAX;
    int tidx = wg % NTMAX;
    if (tidx >= tmn[0]) return;
    int e = tme[tidx];
    int row0 = tmr[tidx];
    int s1 = offs[e + 1];
    int n0 = nt * BN;
    int tid = threadIdx.x;
    if (tid < BM) { int s = row0 + tid; toks[tid] = tid_arr[(s < s1) ? s : (s1 - 1)]; }
    __syncthreads();
    int lane = tid & 63, w = tid >> 6;
    int wrow = (w >> 1) * 64, wcol = (w & 1) * 64;
    int lr = lane & 15, lk = (lane >> 4) * 8;
    int srow = lane >> 2, seg = lane & 3;        // staging: 16 rows/issue, 4 lanes/row
    int tokA0 = toks[w * 32 + srow];
    int tokA1 = toks[w * 32 + 16 + srow];
    const bf16* w1e = w1t + (size_t)e * FHD * HD;
    const bf16* bsrc0 = w1e + (size_t)(n0 + w * 32 + srow) * HD + seg * 8;
    const bf16* bsrc1 = w1e + (size_t)(n0 + w * 32 + 16 + srow) * HD + seg * 8;
    const bf16* asrc0 = xbf + (size_t)tokA0 * HD + seg * 8;
    const bf16* asrc1 = xbf + (size_t)tokA1 * HD + seg * 8;
    bf16* aDst0 = &As[(w * 32) * BK];
    bf16* aDst1 = &As[(w * 32 + 16) * BK];
    bf16* bDst0 = &Bs[(w * 32) * BK];
    bf16* bDst1 = &Bs[(w * 32 + 16) * BK];
    f32x4 acc[4][4] = {};
    for (int k0 = 0; k0 < HD; k0 += BK) {
        gload_lds16(asrc0 + k0, aDst0);
        gload_lds16(asrc1 + k0, aDst1);
        gload_lds16(bsrc0 + k0, bDst0);
        gload_lds16(bsrc1 + k0, bDst1);
        __syncthreads();
        s16x8 aF[4], bF[4];
#pragma unroll
        for (int m = 0; m < 4; ++m) aF[m] = *reinterpret_cast<const s16x8*>(&As[(wrow + m * 16 + lr) * BK + lk]);
#pragma unroll
        for (int n = 0; n < 4; ++n) bF[n] = *reinterpret_cast<const s16x8*>(&Bs[(wcol + n * 16 + lr) * BK + lk]);
#pragma unroll
        for (int m = 0; m < 4; ++m)
#pragma unroll
            for (int n = 0; n < 4; ++n)
                acc[m][n] = __builtin_amdgcn_mfma_f32_16x16x32_bf16(aF[m], bF[n], acc[m][n], 0, 0, 0);
        __syncthreads();
    }
#pragma unroll
    for (int m = 0; m < 4; ++m) {
#pragma unroll
        for (int n = 0; n < 4; ++n) {
            int col = n0 + wcol + n * 16 + lr;
            float bv = b1[(size_t)e * FHD + col];
#pragma unroll
            for (int r = 0; r < 4; ++r) {
                int row = wrow + m * 16 + (lane >> 4) * 4 + r;
                int slot = row0 + row;
                if (slot < s1) {
                    float v2 = acc[m][n][r] + bv;
                    v2 = 0.5f * v2 * (1.0f + erff(v2 * 0.70710678118f));
                    hmid[(size_t)slot * FHD + col] = __float2bfloat16(v2);
                }
            }
        }
    }
}

// GEMM2: ys[slot, :] = hmid[slot, :] @ w2t[e]^T + b2[e]  (f32 out, no scatter)
__global__ __launch_bounds__(256) void gemm2_kernel(const bf16* __restrict__ hmid, const bf16* __restrict__ w2t,
        const float* __restrict__ b2, const int* __restrict__ offs, float* __restrict__ ys,
        const int* __restrict__ tmr, const int* __restrict__ tme, const int* __restrict__ tmn) {
    __shared__ bf16 As[BM * BK];
    __shared__ bf16 Bs[BN * BK];
    int nwg = gridDim.x;
    int orig = blockIdx.x;
    int wg = (orig & 7) * (nwg >> 3) + (orig >> 3);
    int nt = wg / NTMAX;
    int tidx = wg % NTMAX;
    if (tidx >= tmn[0]) return;
    int e = tme[tidx];
    int row0 = tmr[tidx];
    int s1 = offs[e + 1];
    int n0 = nt * BN;
    int tid = threadIdx.x;
    int lane = tid & 63, w = tid >> 6;
    int wrow = (w >> 1) * 64, wcol = (w & 1) * 64;
    int lr = lane & 15, lk = (lane >> 4) * 8;
    int srow = lane >> 2, seg = lane & 3;
    int ar0 = row0 + w * 32 + srow;      if (ar0 >= s1) ar0 = s1 - 1;
    int ar1 = row0 + w * 32 + 16 + srow; if (ar1 >= s1) ar1 = s1 - 1;
    const bf16* w2e = w2t + (size_t)e * HD * FHD;
    const bf16* bsrc0 = w2e + (size_t)(n0 + w * 32 + srow) * FHD + seg * 8;
    const bf16* bsrc1 = w2e + (size_t)(n0 + w * 32 + 16 + srow) * FHD + seg * 8;
    const bf16* asrc0 = hmid + (size_t)ar0 * FHD + seg * 8;
    const bf16* asrc1 = hmid + (size_t)ar1 * FHD + seg * 8;
    bf16* aDst0 = &As[(w * 32) * BK];
    bf16* aDst1 = &As[(w * 32 + 16) * BK];
    bf16* bDst0 = &Bs[(w * 32) * BK];
    bf16* bDst1 = &Bs[(w * 32 + 16) * BK];
    f32x4 acc[4][4] = {};
    for (int k0 = 0; k0 < FHD; k0 += BK) {
        gload_lds16(asrc0 + k0, aDst0);
        gload_lds16(asrc1 + k0, aDst1);
        gload_lds16(bsrc0 + k0, bDst0);
        gload_lds16(bsrc1 + k0, bDst1);
        __syncthreads();
        s16x8 aF[4], bF[4];
#pragma unroll
        for (int m = 0; m < 4; ++m) aF[m] = *reinterpret_cast<const s16x8*>(&As[(wrow + m * 16 + lr) * BK + lk]);
#pragma unroll
        for (int n = 0; n < 4; ++n) bF[n] = *reinterpret_cast<const s16x8*>(&Bs[(wcol + n * 16 + lr) * BK + lk]);
#pragma unroll
        for (int m = 0; m < 4; ++m)
#pragma unroll
            for (int n = 0; n < 4; ++n)
                acc[m][n] = __builtin_amdgcn_mfma_f32_16x16x32_bf16(aF[m], bF[n], acc[m][n], 0, 0, 0);
        __syncthreads();
    }
#pragma unroll
    for (int m = 0; m < 4; ++m) {
#pragma unroll
        for (int n = 0; n < 4; ++n) {
            int col = n0 + wcol + n * 16 + lr;
            float bv = b2[(size_t)e * HD + col];
#pragma unroll
            for (int r = 0; r < 4; ++r) {
                int row = wrow + m * 16 + (lane >> 4) * 4 + r;
                int slot = row0 + row;
                if (slot < s1) ys[(size_t)slot * HD + col] = acc[m][n][r] + bv;
            }
        }
    }
}

// out[t,:] = tw[slot0[t]] * ys[slot0[t],:] + tw[slot1[t]] * ys[slot1[t],:]
__global__ __launch_bounds__(256) void combine_kernel(const float* __restrict__ ys,
        const int* __restrict__ slot0, const int* __restrict__ slot1,
        const float* __restrict__ tw, float* __restrict__ out) {
    int t = blockIdx.x;
    int c = threadIdx.x * 4;
    int sa = slot0[t], sb = slot1[t];
    float wa = tw[sa], wb = tw[sb];
    float4 a = *reinterpret_cast<const float4*>(&ys[(size_t)sa * HD + c]);
    float4 b = *reinterpret_cast<const float4*>(&ys[(size_t)sb * HD + c]);
    float4 o;
    o.x = wa * a.x + wb * b.x; o.y = wa * a.y + wb * b.y;
    o.z = wa * a.z + wb * b.z; o.w = wa * a.w + wb * b.w;
    *reinterpret_cast<float4*>(&out[(size_t)t * HD + c]) = o;
}

extern "C" void kernel_launch(void* const* d_in, const int* in_sizes, int n_in,
                              void* d_out, int out_size, void* d_ws, size_t ws_size,
                              hipStream_t stream) {
    const float* x  = (const float*)d_in[0];
    const float* rw = (const float*)d_in[1];
    const float* rb = (const float*)d_in[2];
    const float* w1 = (const float*)d_in[3];
    const float* b1 = (const float*)d_in[4];
    const float* w2 = (const float*)d_in[5];
    const float* b2 = (const float*)d_in[6];
    float* out = (float*)d_out;
    char* ws = (char*)d_ws;

    int*   counts  = (int*)(ws + OFF_COUNTS);
    int*   cursor  = (int*)(ws + OFF_CURSOR);
    int*   offs    = (int*)(ws + OFF_OFFS);
    int*   e0a     = (int*)(ws + OFF_E0);
    int*   e1a     = (int*)(ws + OFF_E1);
    float* w0a     = (float*)(ws + OFF_W0);
    float* w1a     = (float*)(ws + OFF_W1);
    int*   slot0   = (int*)(ws + OFF_S0);
    int*   slot1   = (int*)(ws + OFF_S1);
    int*   tid_arr = (int*)(ws + OFF_TID);
    float* tw_arr  = (float*)(ws + OFF_TW);
    int*   tmr     = (int*)(ws + OFF_TMR);
    int*   tme     = (int*)(ws + OFF_TME);
    int*   tmn     = (int*)(ws + OFF_TMN);
    bf16*  xbf     = (bf16*)(ws + OFF_XBF);
    bf16*  w1t     = (bf16*)(ws + OFF_W1T);
    bf16*  w2t     = (bf16*)(ws + OFF_W2T);
    bf16*  hmid    = (bf16*)(ws + OFF_HMID);
    float* ys      = (float*)(ws + OFF_YS);

    hipMemsetAsync(counts, 0, 64, stream);

    cast_x_kernel<<<TT * HD / 2048, 256, 0, stream>>>(x, xbf);
    transpose_cast_kernel<<<NE * (HD / 64) * (FHD / 64), 256, 0, stream>>>(w1, w1t, HD, FHD);
    transpose_cast_kernel<<<NE * (FHD / 64) * (HD / 64), 256, 0, stream>>>(w2, w2t, FHD, HD);
    router_kernel<<<TT / 4, 256, 0, stream>>>(x, rw, rb, e0a, e1a, w0a, w1a, counts);
    scan_offsets_kernel<<<1, 64, 0, stream>>>(counts, offs, cursor, tmr, tme, tmn);
    scatter_kernel<<<TT / 256, 256, 0, stream>>>(e0a, e1a, w0a, w1a, cursor, tid_arr, tw_arr, slot0, slot1);
    gemm1_kernel<<<(FHD / BN) * NTMAX, 256, 0, stream>>>(xbf, w1t, b1, offs, tid_arr, hmid, tmr, tme, tmn);
    gemm2_kernel<<<(HD / BN) * NTMAX, 256, 0, stream>>>(hmid, w2t, b2, offs, ys, tmr, tme, tmn);
    combine_kernel<<<TT, 256, 0, stream>>>(ys, slot0, slot1, tw_arr, out);
}